// Round 9
// baseline (6404.060 us; speedup 1.0000x reference)
//
#include <hip/hip_runtime.h>
#include <math.h>

// ---------------- constants ----------------
#define T_STEPS 512
#define NB      64
#define HID     256
#define IN_DIM  512
#define NWG     16     // persistent seq workers

typedef __attribute__((ext_vector_type(8))) short bh8;     // 8 x bf16 (raw bits)
typedef __attribute__((ext_vector_type(4))) float f32x4;
typedef __attribute__((ext_vector_type(4))) unsigned u32x4;

// LDS swizzle: XOR 16B-chunk index with (row&7) to break power-of-2 stride conflicts.
#define SWZ(row, k, Kw) ((row)*(Kw) + ((k) ^ (((row)&7)*8)))

__device__ __forceinline__ float bf2f(unsigned short u) {
  union { unsigned u; float f; } v; v.u = ((unsigned)u) << 16; return v.f;
}
__device__ __forceinline__ unsigned short f2bf(float f) {
  union { float f; unsigned u; } v; v.f = f;
  unsigned r = v.u + 0x7FFFu + ((v.u >> 16) & 1u);   // RNE
  return (unsigned short)(r >> 16);
}
__device__ __forceinline__ float geluf(float x) {
  return 0.5f * x * (1.f + erff(x * 0.70710678118654752f));
}
__device__ __forceinline__ float sigmf_(float x) { return 1.f / (1.f + __expf(-x)); }

__device__ __forceinline__ f32x4 mfma16(bh8 a, bh8 b, f32x4 c) {
  return __builtin_amdgcn_mfma_f32_16x16x32_bf16(a, b, c, 0, 0, 0);
}

// ---- LLC-coherent tagged-word ops (sc0 sc1 proven R3/R5/R6/R8) ----
__device__ __forceinline__ u32x4 ldt4(const unsigned* p) {
  u32x4 r;
  asm volatile("global_load_dwordx4 %0, %1, off sc0 sc1" : "=v"(r) : "v"(p));
  return r;
}
__device__ __forceinline__ void stt(unsigned* p, unsigned w) {
  asm volatile("global_store_dword %0, %1, off sc0 sc1" :: "v"(p), "v"(w) : "memory");
}

// Chunked tagged consume: the lane's 64-word slice splits into 8 chunks of 8 words
// (1 KB per wave per chunk, covering 2 producers). Validate per chunk (__all of
// low-16 tags), unpack, run body(ks, frag) IMMEDIATELY, and reload only the
// still-invalid chunks. Tag semantics identical to R8 (proven): data IS the flag.
template<typename F>
__device__ __forceinline__ void consume_chunks(const unsigned* bp, unsigned tag, F&& body) {
  u32x4 a0[8], a1[8];
  #pragma unroll
  for (int ks = 0; ks < 8; ++ks) { a0[ks] = ldt4(bp + ks*32); a1[ks] = ldt4(bp + ks*32 + 4); }
  asm volatile("s_waitcnt vmcnt(0)" ::: "memory");
  unsigned pending = 0xFFu;            // wave-uniform (updated under __all)
  for (;;) {
    #pragma unroll
    for (int ks = 0; ks < 8; ++ks) {
      if (pending & (1u << ks)) {
        unsigned acc = (a0[ks][0]^tag)|(a0[ks][1]^tag)|(a0[ks][2]^tag)|(a0[ks][3]^tag)
                     | (a1[ks][0]^tag)|(a1[ks][1]^tag)|(a1[ks][2]^tag)|(a1[ks][3]^tag);
        if (__all((acc & 0xFFFFu) == 0u)) {
          union { unsigned u[4]; bh8 v; } c;
          c.u[0] = (a0[ks][0] >> 16) | (a0[ks][1] & 0xFFFF0000u);
          c.u[1] = (a0[ks][2] >> 16) | (a0[ks][3] & 0xFFFF0000u);
          c.u[2] = (a1[ks][0] >> 16) | (a1[ks][1] & 0xFFFF0000u);
          c.u[3] = (a1[ks][2] >> 16) | (a1[ks][3] & 0xFFFF0000u);
          body(ks, c.v);
          pending &= ~(1u << ks);
        }
      }
    }
    if (!pending) break;
    #pragma unroll
    for (int ks = 0; ks < 8; ++ks)
      if (pending & (1u << ks)) { a0[ks] = ldt4(bp + ks*32); a1[ks] = ldt4(bp + ks*32 + 4); }
    asm volatile("s_waitcnt vmcnt(0)" ::: "memory");
  }
  __builtin_amdgcn_sched_barrier(0);
}

// ---------------- prep kernel 1: weight converts + tagged-state init + zeroing ----------------
struct PrepArgs {
  const float *hidden;
  const float *Wp, *Wpo1, *Whh0, *Whh1, *Wih1, *Wih0, *Wpo2, *Wpr1, *Wpr2, *Wd1, *Wd2;
  unsigned short *Wp_b, *Wpo1cat, *Whh0_b, *Whh1_b, *Wih1_b, *WBcat, *Wpo2_b, *Wpr1_b, *Wpr2_b, *Wd1cat, *Wd2_b;
  unsigned *H1t, *h0bt, *QPt;
};

__global__ void prep1(PrepArgs a) {
  const int task = blockIdx.y;
  const int stride = gridDim.x * blockDim.x;
  const int i0 = blockIdx.x * blockDim.x + threadIdx.x;
  switch (task) {
    case 0:  for (int i=i0;i<131072;i+=stride) a.Wp_b[i]   = f2bf(a.Wp[i]);   break;
    case 1:  for (int i=i0;i<131072;i+=stride) a.Wpo1cat[i]= f2bf(a.Wpo1[i]); break;
    case 2:  for (int i=i0;i<196608;i+=stride) a.Whh0_b[i] = f2bf(a.Whh0[i]); break;
    case 3:  for (int i=i0;i<196608;i+=stride) a.Whh1_b[i] = f2bf(a.Whh1[i]); break;
    case 4:  for (int i=i0;i<196608;i+=stride) a.Wih1_b[i] = f2bf(a.Wih1[i]); break;
    case 5:  for (int i=i0;i<196608;i+=stride) { int c=i>>8, k=i&255;
               a.WBcat[c*512+k] = f2bf(a.Wih0[c*384+k]); } break; // x-part of Wih0
    case 6:  for (int i=i0;i<65536;i+=stride)  a.Wpo2_b[i] = f2bf(a.Wpo2[i]); break;
    case 7:  for (int i=i0;i<65536;i+=stride)  a.Wpr1_b[i] = f2bf(a.Wpr1[i]); break;
    case 8:  for (int i=i0;i<65536;i+=stride)  a.Wpr2_b[i] = f2bf(a.Wpr2[i]); break;
    case 9:  for (int i=i0;i<98304;i+=stride)  a.Wd1cat[i] = f2bf(a.Wd1[i]);  break;
    case 10: for (int i=i0;i<262144;i+=stride) a.Wd2_b[i]  = f2bf(a.Wd2[i]);  break;
    // tagged initial state (tag 0):
    case 11: for (int i=i0;i<16384;i+=stride)
               a.H1t[i]  = ((unsigned)f2bf(a.hidden[16384+i])) << 16; break;
    case 12: for (int i=i0;i<16384;i+=stride)
               a.h0bt[i] = ((unsigned)f2bf(a.hidden[i])) << 16;       break;
    // zero tagged exchange buffers (kills stale tags across graph replays):
    case 13: { u32x4 z = {0u,0u,0u,0u};
               u32x4* p = (u32x4*)a.QPt;
               for (int i=i0;i<2097152;i+=stride) p[i] = z; } break;
    case 14: { u32x4 z = {0u,0u,0u,0u};
               u32x4* p = (u32x4*)(a.H1t + 16384);
               for (int i=i0;i<2097152;i+=stride) p[i] = z; } break;
    default: break;
  }
}

// ---------------- prep kernel 2: Wk0 = Wih0[:,256:384] @ Wpo2[:128,:]  (+ bk0) ----------------
__global__ void prep2(const float* __restrict__ Wih0, const float* __restrict__ Wpo2,
                      const float* __restrict__ bih0, const float* __restrict__ bpo2,
                      unsigned short* __restrict__ WBcat, float* __restrict__ bk0) {
  const int c = blockIdx.x;       // 768
  const int k = threadIdx.x;      // 256
  const float* wrow = Wih0 + c*384 + 256;   // 128 z-input weights of row c
  float acc = 0.f;
  for (int j = 0; j < 128; ++j) acc += wrow[j] * Wpo2[j*256 + k];
  WBcat[c*512 + 256 + k] = f2bf(acc);
  if (k == 0) {
    float b = bih0[c];
    for (int j = 0; j < 128; ++j) b += wrow[j] * bpo2[j];
    bk0[c] = b;
  }
}

// ---------------- A-operand loaders for the generic GEMM ----------------
// FMT: 0 = bf16, 1 = f32 (convert), 2 = tagged u32 (bf16 in hi16, strip tag).
template<int FMT>
__device__ __forceinline__ void ldA(const void* A, int lda, int row, int k,
                                    unsigned short* tmp) {
  if constexpr (FMT == 1) {
    const float* p = (const float*)A + (size_t)row*lda + k;
    #pragma unroll
    for (int j = 0; j < 8; ++j) tmp[j] = f2bf(p[j]);
  } else if constexpr (FMT == 2) {
    const unsigned* p = (const unsigned*)A + (size_t)row*lda + k;
    u32x4 a0 = *(const u32x4*)p;
    u32x4 a1 = *(const u32x4*)(p + 4);
    unsigned* t32 = (unsigned*)tmp;
    t32[0] = (a0[0] >> 16) | (a0[1] & 0xFFFF0000u);
    t32[1] = (a0[2] >> 16) | (a0[3] & 0xFFFF0000u);
    t32[2] = (a1[0] >> 16) | (a1[1] & 0xFFFF0000u);
    t32[3] = (a1[2] >> 16) | (a1[3] & 0xFFFF0000u);
  } else {
    *(bh8*)tmp = *(const bh8*)((const unsigned short*)A + (size_t)row*lda + k);
  }
}

// ---------------- generic MFMA GEMM:  C = epi(Acat @ W^T + bias) ----------------
template<int EPI, int A1T, int A2T>
__global__ __launch_bounds__(256, 2) void gemm_k(
    const void* __restrict__ A1_, int lda1, int K1,
    const void* __restrict__ A2_, int lda2, int K2,
    const unsigned short* __restrict__ W, const float* __restrict__ bias,
    void* __restrict__ out_, int M, int N)
{
  __shared__ unsigned short sA[64*64];
  __shared__ unsigned short sW[64*64];
  const int m0 = blockIdx.x * 64, n0 = blockIdx.y * 64;
  const int tid = threadIdx.x, lane = tid & 63, wave = tid >> 6;
  const int Ktot = K1 + K2;
  f32x4 zero = {0.f,0.f,0.f,0.f};
  f32x4 acc[4] = {zero, zero, zero, zero};

  for (int kc = 0; kc < Ktot; kc += 64) {
    __syncthreads();
    #pragma unroll
    for (int i = 0; i < 2; ++i) {
      int cidx = tid*2 + i;
      int r = cidx >> 3, ko = (cidx & 7) * 8;
      int kg = kc + ko;
      alignas(16) unsigned short tmp[8];
      if (kg < K1) ldA<A1T>(A1_, lda1, m0 + r, kg, tmp);
      else         ldA<A2T>(A2_, lda2, m0 + r, kg - K1, tmp);
      *(bh8*)&sA[SWZ(r, ko, 64)] = *(bh8*)tmp;
    }
    #pragma unroll
    for (int i = 0; i < 2; ++i) {
      int cidx = tid*2 + i;
      int r = cidx >> 3, ko = (cidx & 7) * 8;
      const unsigned short* p = W + (size_t)(n0 + r)*Ktot + kc + ko;
      *(bh8*)&sW[SWZ(r, ko, 64)] = *(const bh8*)p;
    }
    __syncthreads();
    #pragma unroll
    for (int ks = 0; ks < 2; ++ks) {
      int k0 = ks*32 + ((lane >> 4) << 3);
      int ar = 16*wave + (lane & 15);
      bh8 a = *(const bh8*)&sA[SWZ(ar, k0, 64)];
      #pragma unroll
      for (int nt = 0; nt < 4; ++nt) {
        int wr = nt*16 + (lane & 15);
        bh8 b = *(const bh8*)&sW[SWZ(wr, k0, 64)];
        acc[nt] = mfma16(a, b, acc[nt]);
      }
    }
  }
  #pragma unroll
  for (int nt = 0; nt < 4; ++nt) {
    int col = n0 + nt*16 + (lane & 15);
    float bv = bias[col];
    #pragma unroll
    for (int r = 0; r < 4; ++r) {
      int row = m0 + 16*wave + ((lane >> 4) << 2) + r;
      float v = acc[nt][r] + bv;
      if constexpr (EPI == 0) {
        ((float*)out_)[(size_t)row*N + col] = v;
      } else if constexpr (EPI == 1) {
        ((unsigned short*)out_)[(size_t)row*N + col] = f2bf(v);
      } else if constexpr (EPI == 2) {
        int b = row >> 9, t = row & 511;           // row = b*T + t
        ((unsigned short*)out_)[((size_t)t*64 + b)*N + col] = f2bf(v);
      } else if constexpr (EPI == 3) {
        ((unsigned short*)out_)[(size_t)row*N + col] = f2bf(geluf(v));
      } else { // 4: decoder, row = t*64 + b, col<512 -> mu, else lv
        int t = row >> 6, b = row & 63;
        float* o = (float*)out_;
        if (col < 512) o[(size_t)b*262144 + (size_t)t*512 + col] = v;
        else o[16777216 + (size_t)b*262144 + (size_t)t*512 + (col - 512)] = v;
      }
    }
  }
}

// ---------------- persistent sequential kernel: tagged chunked dataflow ----------------
// Per step: A{consume H1[t] -> qp1 store} B{consume QP1[t] -> h0 store} C{consume h0b -> H1[t+1]}.
// Consumers overlap MFMAs with chunk arrival; producers never drain (stores fly).
#define SEQ_LDS_BYTES ((16*512 + 48*256 + 48*256 + 48*512 + 48*256) * 2)  // 139264

__global__ __launch_bounds__(256, 1) void seq_kernel(
    const unsigned short* __restrict__ gWQ,   // Wpo1cat [256][512]  ([h|x])
    const unsigned short* __restrict__ gWH0,  // Whh0 [768][256]
    const unsigned short* __restrict__ gWH1,  // Whh1 [768][256]
    const unsigned short* __restrict__ gWB,   // WBcat [768][512]  ([Wih0_x | Wk0])
    const unsigned short* __restrict__ gWI1,  // Wih1 [768][256]
    const float* __restrict__ bpo1, const float* __restrict__ bhh0,
    const float* __restrict__ bhh1, const float* __restrict__ bih1,
    const float* __restrict__ bk0,
    const float* __restrict__ hidden0,        // initial state f32 [2][64][256]
    const unsigned short* __restrict__ Xp,    // [T][64][256] bf16 (read-only, cached)
    unsigned* __restrict__ QPt,               // [T][64][256] tagged u32
    unsigned* __restrict__ H1t,               // [T+1][64][256] tagged u32 (slot0 = init)
    unsigned* __restrict__ h0bt,              // [64][256] tagged u32
    float* __restrict__ outHid)
{
  extern __shared__ unsigned short lds[];
  unsigned short* WQ  = lds;                 // [16][512]
  unsigned short* WH0 = WQ  + 16*512;        // [48][256]
  unsigned short* WH1 = WH0 + 48*256;        // [48][256]
  unsigned short* WB  = WH1 + 48*256;        // [48][512]
  unsigned short* WI1 = WB  + 48*512;        // [48][256]
  const int g = blockIdx.x;
  const int tid = threadIdx.x;
  const int wave = tid >> 6, lane = tid & 63;

  // ---- stage this WG's weight slice into LDS (swizzled) ----
  for (int i = tid; i < 16*64; i += 256) { int p = i >> 6, ci = (i & 63) * 8;
    *(bh8*)&WQ[SWZ(p, ci, 512)] = *(const bh8*)&gWQ[(size_t)(16*g + p)*512 + ci]; }
  for (int i = tid; i < 48*32; i += 256) { int p = i >> 5, ci = (i & 31) * 8;
    int c = ((p >> 4) << 8) + 16*g + (p & 15);
    *(bh8*)&WH0[SWZ(p, ci, 256)] = *(const bh8*)&gWH0[(size_t)c*256 + ci]; }
  for (int i = tid; i < 48*32; i += 256) { int p = i >> 5, ci = (i & 31) * 8;
    int c = ((p >> 4) << 8) + 16*g + (p & 15);
    *(bh8*)&WH1[SWZ(p, ci, 256)] = *(const bh8*)&gWH1[(size_t)c*256 + ci]; }
  for (int i = tid; i < 48*64; i += 256) { int p = i >> 6, ci = (i & 63) * 8;
    int c = ((p >> 4) << 8) + 16*g + (p & 15);
    *(bh8*)&WB[SWZ(p, ci, 512)] = *(const bh8*)&gWB[(size_t)c*512 + ci]; }
  for (int i = tid; i < 48*32; i += 256) { int p = i >> 5, ci = (i & 31) * 8;
    int c = ((p >> 4) << 8) + 16*g + (p & 15);
    *(bh8*)&WI1[SWZ(p, ci, 256)] = *(const bh8*)&gWI1[(size_t)c*256 + ci]; }
  __syncthreads();   // LDS weights read-only afterwards

  const int col   = 16*g + (lane & 15);            // global column 0..255
  const int arow  = 16*wave + (lane & 15);         // A-fragment row (batch)
  const int crow0 = 16*wave + ((lane >> 4) << 2);  // acc row base
  const int koff  = ((lane >> 4) << 3);
  const int l15   = lane & 15;
  const float bq = bpo1[col];
  float bh0v[3], bh1v[3], bi1v[3], bk0v[3];
  #pragma unroll
  for (int e = 0; e < 3; ++e) {
    bh0v[e] = bhh0[e*256 + col]; bh1v[e] = bhh1[e*256 + col];
    bi1v[e] = bih1[e*256 + col]; bk0v[e] = bk0[e*256 + col];
  }
  // private recurrent state in registers
  float h0s[4], h1s[4];
  #pragma unroll
  for (int r = 0; r < 4; ++r) {
    h0s[r] = hidden0[(size_t)(crow0 + r)*HID + col];
    h1s[r] = hidden0[16384 + (size_t)(crow0 + r)*HID + col];
  }
  const f32x4 zero = {0.f,0.f,0.f,0.f};
  const int sliceoff = arow*HID + koff;   // this lane's 64-word slice base

  // ---- preload: gh0a(t=0) from initial h0bt (tag 0); xpr(t=0); aQ1p(t=0) ----
  f32x4 gh0a[3] = {zero, zero, zero};
  consume_chunks(h0bt + sliceoff, 0u, [&](int ks, bh8 f) {
    int k0 = ks*32 + koff;
    #pragma unroll
    for (int e = 0; e < 3; ++e)
      gh0a[e] = mfma16(f, *(const bh8*)&WH0[SWZ(e*16 + l15, k0, 256)], gh0a[e]);
  });
  bh8 xpr[8];
  #pragma unroll
  for (int j = 0; j < 8; ++j) xpr[j] = *(const bh8*)(Xp + (size_t)sliceoff + j*32);
  f32x4 aQ1p = zero;
  #pragma unroll
  for (int ks = 0; ks < 8; ++ks) {
    int k0 = ks*32 + koff;
    aQ1p = mfma16(xpr[ks], *(const bh8*)&WQ[SWZ(l15, 256 + k0, 512)], aQ1p);
  }

  #pragma unroll 1
  for (int t = 0; t < T_STEPS; ++t) {
    const unsigned tagA = (unsigned)t;         // H1 slot t carries tag t
    const unsigned tagN = (unsigned)(t + 1);   // everything produced in step t
    const unsigned* h1slot = H1t + (size_t)t * (NB*HID);
    unsigned* qpslot = QPt + (size_t)t * (NB*HID);

    // ---------- Phase A: qp1 = gelu([h1|x]@Wpo1^T + bpo1) ----------
    // chunked consume of h1: per chunk 1 critical MFMA (aQ0); save frag for gh1a.
    bh8 h1r[8];
    f32x4 aQ0 = zero;
    consume_chunks(h1slot + sliceoff, tagA, [&](int ks, bh8 f) {
      h1r[ks] = f;
      int k0 = ks*32 + koff;
      aQ0 = mfma16(f, *(const bh8*)&WQ[SWZ(l15, k0, 512)], aQ0);
    });
    #pragma unroll
    for (int r = 0; r < 4; ++r) {
      float v = geluf(aQ0[r] + aQ1p[r] + bq);
      stt(qpslot + (size_t)(crow0 + r)*HID + col,
          (((unsigned)f2bf(v)) << 16) | tagN);
    }
    // shadow (store flight overlaps): gh1a from h1r + gi x-part from xpr
    f32x4 gh1a[3] = {zero, zero, zero};
    f32x4 gi[3]   = {zero, zero, zero};
    #pragma unroll
    for (int ks = 0; ks < 8; ++ks) {
      int k0 = ks*32 + koff;
      #pragma unroll
      for (int e = 0; e < 3; ++e) {
        gh1a[e] = mfma16(h1r[ks], *(const bh8*)&WH1[SWZ(e*16 + l15, k0, 256)], gh1a[e]);
        gi[e]   = mfma16(xpr[ks], *(const bh8*)&WB[SWZ(e*16 + l15, k0, 512)], gi[e]);
      }
    }

    // ---------- Phase B: gi += qp-part ; h0 = GRU(gi, gh0a, h0s) ----------
    consume_chunks(qpslot + sliceoff, tagN, [&](int ks, bh8 f) {
      int k0 = ks*32 + koff;
      #pragma unroll
      for (int e = 0; e < 3; ++e)
        gi[e] = mfma16(f, *(const bh8*)&WB[SWZ(e*16 + l15, 256 + k0, 512)], gi[e]);
    });
    #pragma unroll
    for (int r = 0; r < 4; ++r) {
      float rr = sigmf_(gi[0][r] + bk0v[0] + gh0a[0][r] + bh0v[0]);
      float zz = sigmf_(gi[1][r] + bk0v[1] + gh0a[1][r] + bh0v[1]);
      float nn = tanhf(gi[2][r] + bk0v[2] + rr*(gh0a[2][r] + bh0v[2]));
      float hn = (1.f - zz)*nn + zz*h0s[r];
      h0s[r] = hn;
      stt(h0bt + (size_t)(crow0 + r)*HID + col,
          (((unsigned)f2bf(hn)) << 16) | tagN);
    }
    // xpr(t+1) prefetch (plain cached) — rides under C's consume
    if (t + 1 < T_STEPS) {
      const unsigned short* xq = Xp + (size_t)(t + 1) * (NB*HID);
      #pragma unroll
      for (int j = 0; j < 8; ++j) xpr[j] = *(const bh8*)(xq + (size_t)sliceoff + j*32);
    }

    // ---------- Phase C: gi1 = h0@Wih1^T + bih1 ; h1 = GRU(gi1, gh1a, h1s) ----------
    bh8 h0n[8];
    f32x4 gi1[3] = {zero, zero, zero};
    consume_chunks(h0bt + sliceoff, tagN, [&](int ks, bh8 f) {
      h0n[ks] = f;
      int k0 = ks*32 + koff;
      #pragma unroll
      for (int e = 0; e < 3; ++e)
        gi1[e] = mfma16(f, *(const bh8*)&WI1[SWZ(e*16 + l15, k0, 256)], gi1[e]);
    });
    unsigned* h1next = H1t + (size_t)(t + 1) * (NB*HID);
    #pragma unroll
    for (int r = 0; r < 4; ++r) {
      float rr = sigmf_(gi1[0][r] + bi1v[0] + gh1a[0][r] + bh1v[0]);
      float zz = sigmf_(gi1[1][r] + bi1v[1] + gh1a[1][r] + bh1v[1]);
      float nn = tanhf(gi1[2][r] + bi1v[2] + rr*(gh1a[2][r] + bh1v[2]));
      float hv = (1.f - zz)*nn + zz*h1s[r];
      h1s[r] = hv;
      stt(h1next + (size_t)(crow0 + r)*HID + col,
          (((unsigned)f2bf(hv)) << 16) | tagN);
    }
    // shadow: gh0a(t+1) from h0n + aQ1p(t+1) from xpr(t+1)
    if (t + 1 < T_STEPS) {
      gh0a[0] = zero; gh0a[1] = zero; gh0a[2] = zero;
      aQ1p = zero;
      #pragma unroll
      for (int ks = 0; ks < 8; ++ks) {
        int k0 = ks*32 + koff;
        #pragma unroll
        for (int e = 0; e < 3; ++e)
          gh0a[e] = mfma16(h0n[ks], *(const bh8*)&WH0[SWZ(e*16 + l15, k0, 256)], gh0a[e]);
        aQ1p = mfma16(xpr[ks], *(const bh8*)&WQ[SWZ(l15, 256 + k0, 512)], aQ1p);
      }
    }
  }

  // final hidden: each thread writes its own (row, col) cells from registers
  #pragma unroll
  for (int r = 0; r < 4; ++r) {
    int row = crow0 + r;
    outHid[(size_t)row*HID + col]         = h0s[r];
    outHid[16384 + (size_t)row*HID + col] = h1s[r];
  }
}

// ---------------- KL reduction ----------------
__global__ void kl1(const float* __restrict__ Q, const unsigned short* __restrict__ Ppb,
                    float* __restrict__ part) {
  const int m0 = blockIdx.x * 64;
  float s = 0.f;
  for (int i = threadIdx.x; i < 64*128; i += 256) {
    int m = m0 + (i >> 7), j = i & 127;
    float qm = Q[(size_t)m*256 + j],        ql = Q[(size_t)m*256 + 128 + j];
    float pm = bf2f(Ppb[(size_t)m*256 + j]), pl = bf2f(Ppb[(size_t)m*256 + 128 + j]);
    float d = qm - pm;
    s += 0.5f * (pl - ql + (expf(ql) + d*d) * expf(-pl) - 1.f);
  }
  for (int o = 32; o > 0; o >>= 1) s += __shfl_down(s, o);
  __shared__ float red[4];
  if ((threadIdx.x & 63) == 0) red[threadIdx.x >> 6] = s;
  __syncthreads();
  if (threadIdx.x == 0) part[blockIdx.x] = red[0] + red[1] + red[2] + red[3];
}
__global__ void kl2(const float* __restrict__ part, float* __restrict__ out) {
  float s = 0.f;
  for (int i = threadIdx.x; i < 512; i += 256) s += part[i];
  for (int o = 32; o > 0; o >>= 1) s += __shfl_down(s, o);
  __shared__ float red[4];
  if ((threadIdx.x & 63) == 0) red[threadIdx.x >> 6] = s;
  __syncthreads();
  if (threadIdx.x == 0) out[0] = (red[0] + red[1] + red[2] + red[3]) / 32768.f;
}

// ---------------- host launch ----------------
extern "C" void kernel_launch(void* const* d_in, const int* in_sizes, int n_in,
                              void* d_out, int out_size, void* d_ws, size_t ws_size,
                              hipStream_t stream) {
  const float* x_seq  = (const float*)d_in[0];
  const float* hidden = (const float*)d_in[1];
  const float* Wp   = (const float*)d_in[2];  const float* bp   = (const float*)d_in[3];
  const float* Wih0 = (const float*)d_in[4];  const float* Whh0 = (const float*)d_in[5];
  const float* bih0 = (const float*)d_in[6];  const float* bhh0 = (const float*)d_in[7];
  const float* Wih1 = (const float*)d_in[8];  const float* Whh1 = (const float*)d_in[9];
  const float* bih1 = (const float*)d_in[10]; const float* bhh1 = (const float*)d_in[11];
  const float* Wpr1 = (const float*)d_in[12]; const float* bpr1 = (const float*)d_in[13];
  const float* Wpr2 = (const float*)d_in[14]; const float* bpr2 = (const float*)d_in[15];
  const float* Wpo1 = (const float*)d_in[16]; const float* bpo1 = (const float*)d_in[17];
  const float* Wpo2 = (const float*)d_in[18]; const float* bpo2 = (const float*)d_in[19];
  const float* Wd1  = (const float*)d_in[20]; const float* bd1  = (const float*)d_in[21];
  const float* Wd2  = (const float*)d_in[22]; const float* bd2  = (const float*)d_in[23];

  char* ws = (char*)d_ws;
  char* Ob = (char*)d_out;
  float* O = (float*)d_out;

  // d_out scratch map (all consumed before the decoder GEMM rewrites d_out):
  unsigned short* Xp  = (unsigned short*)(Ob);             // [0,16MiB) bf16
  unsigned*       QPt = (unsigned*)(Ob + (16u << 20));     // [16,48MiB) tagged u32
  unsigned*       H1t = (unsigned*)(Ob + (48u << 20));     // [48,80.07MiB) tagged u32 (T+1 slots)
  float*          Q   = (float*)(Ob + (81u << 20));        // [81,113MiB) f32
  unsigned short* P1b = (unsigned short*)(Ob);             // reuses Xp after seq
  unsigned short* Ppb = (unsigned short*)(Ob + (16u << 20)); // reuses QPt after Q-GEMM

  // d_ws layout (~20.45 MB)
  unsigned short* D1b     = (unsigned short*)(ws + 0);     // 16 MiB
  char* wb = ws + 16777216;
  unsigned short* Wp_b    = (unsigned short*)(wb + 0);
  unsigned short* Wpo1cat = (unsigned short*)(wb + 262144);
  unsigned short* Whh0_b  = (unsigned short*)(wb + 524288);
  unsigned short* Whh1_b  = (unsigned short*)(wb + 917504);
  unsigned short* Wih1_b  = (unsigned short*)(wb + 1310720);
  unsigned short* WBcat   = (unsigned short*)(wb + 1703936);
  unsigned short* Wpo2_b  = (unsigned short*)(wb + 2490368);
  unsigned short* Wpr1_b  = (unsigned short*)(wb + 2621440);
  unsigned short* Wpr2_b  = (unsigned short*)(wb + 2752512);
  unsigned short* Wd1cat  = (unsigned short*)(wb + 2883584);
  unsigned short* Wd2_b   = (unsigned short*)(wb + 3080192);
  float*    bk0   = (float*)(ws + 20381696);               // 3 KiB
  unsigned* h0bt  = (unsigned*)(ws + 20385792);            // 64 KiB tagged u32
  float*    klpart= (float*)(ws + 20451328);               // 2 KiB

  // ---- prep ----
  PrepArgs pa;
  pa.hidden = hidden;
  pa.Wp = Wp; pa.Wpo1 = Wpo1; pa.Whh0 = Whh0; pa.Whh1 = Whh1; pa.Wih1 = Wih1;
  pa.Wih0 = Wih0; pa.Wpo2 = Wpo2; pa.Wpr1 = Wpr1; pa.Wpr2 = Wpr2; pa.Wd1 = Wd1; pa.Wd2 = Wd2;
  pa.Wp_b = Wp_b; pa.Wpo1cat = Wpo1cat; pa.Whh0_b = Whh0_b; pa.Whh1_b = Whh1_b;
  pa.Wih1_b = Wih1_b; pa.WBcat = WBcat; pa.Wpo2_b = Wpo2_b; pa.Wpr1_b = Wpr1_b;
  pa.Wpr2_b = Wpr2_b; pa.Wd1cat = Wd1cat; pa.Wd2_b = Wd2_b;
  pa.H1t = H1t; pa.h0bt = h0bt; pa.QPt = QPt;
  prep1<<<dim3(64, 15), 256, 0, stream>>>(pa);
  prep2<<<768, 256, 0, stream>>>(Wih0, Wpo2, bih0, bpo2, WBcat, bk0);

  // ---- x-projection: Xp[t][b][:] = x_seq@Wp^T + bp (bf16, bt-transposed) ----
  gemm_k<2, 1, 0><<<dim3(512, 4), 256, 0, stream>>>(
      x_seq, 512, 512, nullptr, 0, 0, Wp_b, bp, Xp, 32768, 256);

  // ---- sequential scan (persistent, 16 WGs, tagged chunked dataflow) ----
  (void)hipFuncSetAttribute((const void*)seq_kernel,
                            hipFuncAttributeMaxDynamicSharedMemorySize, SEQ_LDS_BYTES);
  seq_kernel<<<NWG, 256, SEQ_LDS_BYTES, stream>>>(
      Wpo1cat, Whh0_b, Whh1_b, WBcat, Wih1_b,
      bpo1, bhh0, bhh1, bih1, bk0, hidden,
      Xp, QPt, H1t, h0bt, O + 33554433);

  // ---- deferred parallel phase ----
  // posterior q (f32) from tagged QP1
  gemm_k<0, 2, 0><<<dim3(512, 4), 256, 0, stream>>>(
      QPt, 256, 256, nullptr, 0, 0, Wpo2_b, bpo2, Q, 32768, 256);
  // prior layer 1 from tagged H1 slots 0..T-1 -> P1b (reuses Xp region)
  gemm_k<3, 2, 0><<<dim3(512, 4), 256, 0, stream>>>(
      H1t, 256, 256, nullptr, 0, 0, Wpr1_b, bpr1, P1b, 32768, 256);
  // prior layer 2 -> Ppb (reuses QPt region, already consumed)
  gemm_k<1, 0, 0><<<dim3(512, 4), 256, 0, stream>>>(
      P1b, 256, 256, nullptr, 0, 0, Wpr2_b, bpr2, Ppb, 32768, 256);
  kl1<<<512, 256, 0, stream>>>(Q, Ppb, klpart);
  kl2<<<1, 256, 0, stream>>>(klpart, O + 33554432);
  // decoder layer 1: gelu([h1_t | z_t]@Wd1^T + bd1) from tagged H1 slots 1..T + Q
  gemm_k<3, 2, 1><<<dim3(512, 4), 256, 0, stream>>>(
      H1t + 16384, 256, 256, Q, 256, 128, Wd1cat, bd1, D1b, 32768, 256);
  // decoder layer 2 -> pred_mu / pred_lv (rewrites all of d_out scratch)
  gemm_k<4, 0, 0><<<dim3(512, 16), 256, 0, stream>>>(
      D1b, 256, 256, nullptr, 0, 0, Wd2_b, bd2, (void*)O, 32768, 1024);

  (void)in_sizes; (void)n_in; (void)out_size; (void)ws_size;
}

// Round 10
// 4767.617 us; speedup vs baseline: 1.3432x; 1.3432x over previous
//
#include <hip/hip_runtime.h>
#include <math.h>

// ---------------- constants ----------------
#define T_STEPS 512
#define NB      64
#define HID     256
#define IN_DIM  512
#define NWG     16     // persistent seq workers (co-residency proven R1/R3/R5/R6)

typedef __attribute__((ext_vector_type(8))) short bh8;   // 8 x bf16 (raw bits)
typedef __attribute__((ext_vector_type(4))) float f32x4;

// LDS swizzle: XOR 16B-chunk index with (row&7) to break power-of-2 stride conflicts.
#define SWZ(row, k, Kw) ((row)*(Kw) + ((k) ^ (((row)&7)*8)))

// Blocked exchange layout: elem(row,col) -> buf[(col>>4)*1024 + row*16 + (col&15)].
// Every 128B LLC line is written by exactly ONE wave of ONE CU (no cross-CU
// partial-line combining) and read as contiguous spans.
#define BADDR(row, col) ((((col) >> 4) << 10) + ((row) << 4) + ((col) & 15))

__device__ __forceinline__ float bf2f(unsigned short u) {
  union { unsigned u; float f; } v; v.u = ((unsigned)u) << 16; return v.f;
}
__device__ __forceinline__ unsigned short f2bf(float f) {
  union { float f; unsigned u; } v; v.f = f;
  unsigned r = v.u + 0x7FFFu + ((v.u >> 16) & 1u);   // RNE
  return (unsigned short)(r >> 16);
}
__device__ __forceinline__ float geluf(float x) {
  return 0.5f * x * (1.f + erff(x * 0.70710678118654752f));
}
__device__ __forceinline__ float sigmf_(float x) { return 1.f / (1.f + __expf(-x)); }

__device__ __forceinline__ f32x4 mfma16(bh8 a, bh8 b, f32x4 c) {
  return __builtin_amdgcn_mfma_f32_16x16x32_bf16(a, b, c, 0, 0, 0);
}

// ---- LLC-coherent access (device coherence point; PROVEN R3/R5/R6) ----
__device__ __forceinline__ bh8 ldsh(const unsigned short* p) {
  bh8 r;
  asm volatile("global_load_dwordx4 %0, %1, off sc0 sc1" : "=v"(r) : "v"(p));
  return r;
}
__device__ __forceinline__ void stsh(unsigned short* p, unsigned short v) {
  unsigned v32 = v;
  asm volatile("global_store_short %0, %1, off sc0 sc1" :: "v"(p), "v"(v32) : "memory");
}
__device__ __forceinline__ void waitv0() {
  asm volatile("s_waitcnt vmcnt(0)" ::: "memory");
  __builtin_amdgcn_sched_barrier(0);
}

// ---------------- prep kernel 1: weight converts + inits ----------------
struct PrepArgs {
  const float *hidden;
  const float *Wp, *Wpo1, *Whh0, *Whh1, *Wih1, *Wih0, *Wpo2, *Wpr1, *Wpr2, *Wd1, *Wd2;
  unsigned short *Wp_b, *Wpo1cat, *Whh0_b, *Whh1_b, *Wih1_b, *WBcat, *Wpo2_b, *Wpr1_b, *Wpr2_b, *Wd1cat, *Wd2_b;
  unsigned short *H1_0, *h0b;
  unsigned *flags;
};

__global__ void prep1(PrepArgs a) {
  const int task = blockIdx.y;
  const int stride = gridDim.x * blockDim.x;
  const int i0 = blockIdx.x * blockDim.x + threadIdx.x;
  switch (task) {
    case 0:  for (int i=i0;i<131072;i+=stride) a.Wp_b[i]   = f2bf(a.Wp[i]);   break;
    case 1:  for (int i=i0;i<131072;i+=stride) a.Wpo1cat[i]= f2bf(a.Wpo1[i]); break;
    case 2:  for (int i=i0;i<196608;i+=stride) a.Whh0_b[i] = f2bf(a.Whh0[i]); break;
    case 3:  for (int i=i0;i<196608;i+=stride) a.Whh1_b[i] = f2bf(a.Whh1[i]); break;
    case 4:  for (int i=i0;i<196608;i+=stride) a.Wih1_b[i] = f2bf(a.Wih1[i]); break;
    case 5:  for (int i=i0;i<196608;i+=stride) { int c=i>>8, k=i&255;
               a.WBcat[c*512+k] = f2bf(a.Wih0[c*384+k]); } break; // x-part of Wih0
    case 6:  for (int i=i0;i<65536;i+=stride)  a.Wpo2_b[i] = f2bf(a.Wpo2[i]); break;
    case 7:  for (int i=i0;i<65536;i+=stride)  a.Wpr1_b[i] = f2bf(a.Wpr1[i]); break;
    case 8:  for (int i=i0;i<65536;i+=stride)  a.Wpr2_b[i] = f2bf(a.Wpr2[i]); break;
    case 9:  for (int i=i0;i<98304;i+=stride)  a.Wd1cat[i] = f2bf(a.Wd1[i]);  break;
    case 10: for (int i=i0;i<262144;i+=stride) a.Wd2_b[i]  = f2bf(a.Wd2[i]);  break;
    // blocked initial state:
    case 11: for (int i=i0;i<16384;i+=stride) { int r=i>>8, c=i&255;
               a.H1_0[BADDR(r,c)] = f2bf(a.hidden[16384+i]); } break;
    case 12: for (int i=i0;i<16384;i+=stride) { int r=i>>8, c=i&255;
               a.h0b[BADDR(r,c)]  = f2bf(a.hidden[i]); } break;
    case 15: for (int i=i0;i<2048;i+=stride)   a.flags[i] = 0u;  break;
    default: break;
  }
}

// ---------------- prep kernel 2: Wk0 = Wih0[:,256:384] @ Wpo2[:128,:]  (+ bk0) ----------------
__global__ void prep2(const float* __restrict__ Wih0, const float* __restrict__ Wpo2,
                      const float* __restrict__ bih0, const float* __restrict__ bpo2,
                      unsigned short* __restrict__ WBcat, float* __restrict__ bk0) {
  const int c = blockIdx.x;       // 768
  const int k = threadIdx.x;      // 256
  const float* wrow = Wih0 + c*384 + 256;   // 128 z-input weights of row c
  float acc = 0.f;
  for (int j = 0; j < 128; ++j) acc += wrow[j] * Wpo2[j*256 + k];
  WBcat[c*512 + 256 + k] = f2bf(acc);
  if (k == 0) {
    float b = bih0[c];
    for (int j = 0; j < 128; ++j) b += wrow[j] * bpo2[j];
    bk0[c] = b;
  }
}

// ---------------- A-operand loaders for the generic GEMM ----------------
// FMT: 0 = bf16 row-major, 1 = f32 row-major (convert),
//      3 = blocked bf16 [t][16][64][16] with GEMM row = t*64 + b.
template<int FMT>
__device__ __forceinline__ void ldA(const void* A, int lda, int row, int k,
                                    unsigned short* tmp) {
  if constexpr (FMT == 1) {
    const float* p = (const float*)A + (size_t)row*lda + k;
    #pragma unroll
    for (int j = 0; j < 8; ++j) tmp[j] = f2bf(p[j]);
  } else if constexpr (FMT == 3) {
    const unsigned short* p = (const unsigned short*)A
        + ((size_t)(row >> 6))*16384 + (size_t)(k >> 4)*1024
        + (size_t)(row & 63)*16 + (k & 15);
    *(bh8*)tmp = *(const bh8*)p;
  } else {
    *(bh8*)tmp = *(const bh8*)((const unsigned short*)A + (size_t)row*lda + k);
  }
}

// ---------------- generic MFMA GEMM:  C = epi(Acat @ W^T + bias) ----------------
template<int EPI, int A1T, int A2T>
__global__ __launch_bounds__(256, 2) void gemm_k(
    const void* __restrict__ A1_, int lda1, int K1,
    const void* __restrict__ A2_, int lda2, int K2,
    const unsigned short* __restrict__ W, const float* __restrict__ bias,
    void* __restrict__ out_, int M, int N)
{
  __shared__ unsigned short sA[64*64];
  __shared__ unsigned short sW[64*64];
  const int m0 = blockIdx.x * 64, n0 = blockIdx.y * 64;
  const int tid = threadIdx.x, lane = tid & 63, wave = tid >> 6;
  const int Ktot = K1 + K2;
  f32x4 zero = {0.f,0.f,0.f,0.f};
  f32x4 acc[4] = {zero, zero, zero, zero};

  for (int kc = 0; kc < Ktot; kc += 64) {
    __syncthreads();
    #pragma unroll
    for (int i = 0; i < 2; ++i) {
      int cidx = tid*2 + i;
      int r = cidx >> 3, ko = (cidx & 7) * 8;
      int kg = kc + ko;
      alignas(16) unsigned short tmp[8];
      if (kg < K1) ldA<A1T>(A1_, lda1, m0 + r, kg, tmp);
      else         ldA<A2T>(A2_, lda2, m0 + r, kg - K1, tmp);
      *(bh8*)&sA[SWZ(r, ko, 64)] = *(bh8*)tmp;
    }
    #pragma unroll
    for (int i = 0; i < 2; ++i) {
      int cidx = tid*2 + i;
      int r = cidx >> 3, ko = (cidx & 7) * 8;
      const unsigned short* p = W + (size_t)(n0 + r)*Ktot + kc + ko;
      *(bh8*)&sW[SWZ(r, ko, 64)] = *(const bh8*)p;
    }
    __syncthreads();
    #pragma unroll
    for (int ks = 0; ks < 2; ++ks) {
      int k0 = ks*32 + ((lane >> 4) << 3);
      int ar = 16*wave + (lane & 15);
      bh8 a = *(const bh8*)&sA[SWZ(ar, k0, 64)];
      #pragma unroll
      for (int nt = 0; nt < 4; ++nt) {
        int wr = nt*16 + (lane & 15);
        bh8 b = *(const bh8*)&sW[SWZ(wr, k0, 64)];
        acc[nt] = mfma16(a, b, acc[nt]);
      }
    }
  }
  #pragma unroll
  for (int nt = 0; nt < 4; ++nt) {
    int col = n0 + nt*16 + (lane & 15);
    float bv = bias[col];
    #pragma unroll
    for (int r = 0; r < 4; ++r) {
      int row = m0 + 16*wave + ((lane >> 4) << 2) + r;
      float v = acc[nt][r] + bv;
      if constexpr (EPI == 0) {
        ((float*)out_)[(size_t)row*N + col] = v;
      } else if constexpr (EPI == 1) {
        ((unsigned short*)out_)[(size_t)row*N + col] = f2bf(v);
      } else if constexpr (EPI == 2) {
        int b = row >> 9, t = row & 511;           // row = b*T + t
        ((unsigned short*)out_)[((size_t)t*64 + b)*N + col] = f2bf(v);
      } else if constexpr (EPI == 3) {
        ((unsigned short*)out_)[(size_t)row*N + col] = f2bf(geluf(v));
      } else { // 4: decoder, row = t*64 + b, col<512 -> mu, else lv
        int t = row >> 6, b = row & 63;
        float* o = (float*)out_;
        if (col < 512) o[(size_t)b*262144 + (size_t)t*512 + col] = v;
        else o[16777216 + (size_t)b*262144 + (size_t)t*512 + (col - 512)] = v;
      }
    }
  }
}

// ---------------- per-WAVE split barrier (4 independent planes, no syncthreads) ----------------
// Wave (g,w) owns batch rows [16w,16w+16). flags slot = (g*4+w)*32 dwords (128B-exclusive).
__device__ __forceinline__ void wbar_arrive(unsigned* flags, int g, int w, int lane, unsigned epoch) {
  asm volatile("s_waitcnt vmcnt(0)" ::: "memory");  // this wave's LLC stores complete
  if (lane == 0) {
    unsigned* fp = flags + (g*4 + w)*32;
    asm volatile("global_store_dword %0, %1, off sc0 sc1" :: "v"(fp), "v"(epoch) : "memory");
  }
}
__device__ __forceinline__ void wbar_wait(unsigned* flags, int w, int lane, unsigned epoch) {
  if (lane < NWG) {
    const unsigned* fp = flags + (lane*4 + w)*32;
    unsigned v;
    do {
      asm volatile("global_load_dword %0, %1, off sc0 sc1\n\ts_waitcnt vmcnt(0)"
                   : "=v"(v) : "v"(fp) : "memory");
    } while (v < epoch);
  }
  __builtin_amdgcn_sched_barrier(0);
}

// ---------------- persistent sequential kernel: 512 steps x 3 phases ----------------
// Identical structure to R6 (proven 5313us); only the exchange-buffer LAYOUT changed
// (blocked per-producer lines) + 128B-exclusive flag lines.
#define SEQ_LDS_BYTES ((16*512 + 48*256 + 48*256 + 48*512 + 48*256) * 2)  // 139264

__global__ __launch_bounds__(256, 1) void seq_kernel(
    const unsigned short* __restrict__ gWQ,   // Wpo1cat [256][512]  ([h|x])
    const unsigned short* __restrict__ gWH0,  // Whh0 [768][256]
    const unsigned short* __restrict__ gWH1,  // Whh1 [768][256]
    const unsigned short* __restrict__ gWB,   // WBcat [768][512]  ([Wih0_x | Wk0])
    const unsigned short* __restrict__ gWI1,  // Wih1 [768][256]
    const float* __restrict__ bpo1, const float* __restrict__ bhh0,
    const float* __restrict__ bhh1, const float* __restrict__ bih1,
    const float* __restrict__ bk0,
    const float* __restrict__ hidden0,        // initial state f32 [2][64][256]
    const unsigned short* __restrict__ Xp,    // [T][64][256] bf16 (read-only, cached)
    unsigned short* __restrict__ QP1,         // [T] x blocked [16][64][16] bf16
    unsigned short* __restrict__ H1,          // [T+1] x blocked (slot0 = init)
    unsigned short* __restrict__ h0b,         // blocked [16][64][16] bf16
    unsigned* __restrict__ flags,
    float* __restrict__ outHid)
{
  extern __shared__ unsigned short lds[];
  unsigned short* WQ  = lds;                 // [16][512]
  unsigned short* WH0 = WQ  + 16*512;        // [48][256]
  unsigned short* WH1 = WH0 + 48*256;        // [48][256]
  unsigned short* WB  = WH1 + 48*256;        // [48][512]
  unsigned short* WI1 = WB  + 48*512;        // [48][256]
  const int g = blockIdx.x;
  const int tid = threadIdx.x;
  const int wave = tid >> 6, lane = tid & 63;

  // ---- stage this WG's weight slice into LDS (swizzled) ----
  for (int i = tid; i < 16*64; i += 256) { int p = i >> 6, ci = (i & 63) * 8;
    *(bh8*)&WQ[SWZ(p, ci, 512)] = *(const bh8*)&gWQ[(size_t)(16*g + p)*512 + ci]; }
  for (int i = tid; i < 48*32; i += 256) { int p = i >> 5, ci = (i & 31) * 8;
    int c = ((p >> 4) << 8) + 16*g + (p & 15);
    *(bh8*)&WH0[SWZ(p, ci, 256)] = *(const bh8*)&gWH0[(size_t)c*256 + ci]; }
  for (int i = tid; i < 48*32; i += 256) { int p = i >> 5, ci = (i & 31) * 8;
    int c = ((p >> 4) << 8) + 16*g + (p & 15);
    *(bh8*)&WH1[SWZ(p, ci, 256)] = *(const bh8*)&gWH1[(size_t)c*256 + ci]; }
  for (int i = tid; i < 48*64; i += 256) { int p = i >> 6, ci = (i & 63) * 8;
    int c = ((p >> 4) << 8) + 16*g + (p & 15);
    *(bh8*)&WB[SWZ(p, ci, 512)] = *(const bh8*)&gWB[(size_t)c*512 + ci]; }
  for (int i = tid; i < 48*32; i += 256) { int p = i >> 5, ci = (i & 31) * 8;
    int c = ((p >> 4) << 8) + 16*g + (p & 15);
    *(bh8*)&WI1[SWZ(p, ci, 256)] = *(const bh8*)&gWI1[(size_t)c*256 + ci]; }
  __syncthreads();   // LDS weights read-only after this; no syncthreads in the loop

  const int col   = 16*g + (lane & 15);            // global column 0..255
  const int arow  = 16*wave + (lane & 15);         // A-fragment row (batch)
  const int crow0 = 16*wave + ((lane >> 4) << 2);  // acc row base
  const int koff  = ((lane >> 4) << 3);
  const int l15   = lane & 15;
  const float bq = bpo1[col];
  float bh0v[3], bh1v[3], bi1v[3], bk0v[3];
  #pragma unroll
  for (int e = 0; e < 3; ++e) {
    bh0v[e] = bhh0[e*256 + col]; bh1v[e] = bhh1[e*256 + col];
    bi1v[e] = bih1[e*256 + col]; bk0v[e] = bk0[e*256 + col];
  }
  // ---- private recurrent state in registers ----
  float h0s[4], h1s[4];
  #pragma unroll
  for (int r = 0; r < 4; ++r) {
    h0s[r] = hidden0[(size_t)(crow0 + r)*HID + col];
    h1s[r] = hidden0[16384 + (size_t)(crow0 + r)*HID + col];
  }
  const f32x4 zero = {0.f,0.f,0.f,0.f};
  // producer store base index for this thread (blocked): g-block, own rows, own col
  const int pst = (g << 10) + l15;   // + (crow0+r)*16
  unsigned epoch = 0;

  // ---- preload: gh0a(t=0) from initial h0b; xpr(t=0); aQ1p(t=0) ----
  f32x4 gh0a[3] = {zero, zero, zero};
  {
    bh8 h0i[8];
    #pragma unroll
    for (int j = 0; j < 8; ++j) h0i[j] = ldsh(h0b + BADDR(arow, j*32 + koff));
    waitv0();
    #pragma unroll
    for (int ks = 0; ks < 8; ++ks) {
      int k0 = ks*32 + koff;
      #pragma unroll
      for (int e = 0; e < 3; ++e)
        gh0a[e] = mfma16(h0i[ks], *(const bh8*)&WH0[SWZ(e*16 + l15, k0, 256)], gh0a[e]);
    }
  }
  bh8 xpr[8];
  #pragma unroll
  for (int j = 0; j < 8; ++j) xpr[j] = *(const bh8*)(Xp + (size_t)arow*HID + j*32 + koff);
  f32x4 aQ1p = zero;
  #pragma unroll
  for (int ks = 0; ks < 8; ++ks) {
    int k0 = ks*32 + koff;
    aQ1p = mfma16(xpr[ks], *(const bh8*)&WQ[SWZ(l15, 256 + k0, 512)], aQ1p);
  }

  #pragma unroll 1
  for (int t = 0; t < T_STEPS; ++t) {
    const unsigned short* h1slot = H1 + (size_t)t * (NB*HID);
    unsigned short* qpslot = QP1 + (size_t)t * (NB*HID);

    // ---------- Phase A: qp1 = gelu([h1|x]@Wpo1^T + bpo1) ----------
    bh8 h1r[8];
    #pragma unroll
    for (int j = 0; j < 8; ++j) h1r[j] = ldsh(h1slot + BADDR(arow, j*32 + koff));
    waitv0();
    f32x4 aQ0 = zero;
    #pragma unroll
    for (int ks = 0; ks < 8; ++ks) {
      int k0 = ks*32 + koff;
      aQ0 = mfma16(h1r[ks], *(const bh8*)&WQ[SWZ(l15, k0, 512)], aQ0);
    }
    #pragma unroll
    for (int r = 0; r < 4; ++r) {
      float v = geluf(aQ0[r] + aQ1p[r] + bq);
      stsh(qpslot + pst + ((crow0 + r) << 4), f2bf(v));
    }
    // shadow (store flight overlaps): gh1a from h1r + gi x-part from xpr
    f32x4 gh1a[3] = {zero, zero, zero};
    f32x4 gi[3]   = {zero, zero, zero};
    #pragma unroll
    for (int ks = 0; ks < 8; ++ks) {
      int k0 = ks*32 + koff;
      #pragma unroll
      for (int e = 0; e < 3; ++e) {
        gh1a[e] = mfma16(h1r[ks], *(const bh8*)&WH1[SWZ(e*16 + l15, k0, 256)], gh1a[e]);
        gi[e]   = mfma16(xpr[ks], *(const bh8*)&WB[SWZ(e*16 + l15, k0, 512)], gi[e]);
      }
    }
    ++epoch;
    wbar_arrive(flags, g, wave, lane, epoch);
    wbar_wait(flags, wave, lane, epoch);

    // ---------- Phase B: gi += qp-part ; h0 = GRU(gi, gh0a, h0s) ----------
    bh8 qpr[8];
    #pragma unroll
    for (int j = 0; j < 8; ++j) qpr[j] = ldsh(qpslot + BADDR(arow, j*32 + koff));
    waitv0();
    #pragma unroll
    for (int ks = 0; ks < 8; ++ks) {
      int k0 = ks*32 + koff;
      #pragma unroll
      for (int e = 0; e < 3; ++e)
        gi[e] = mfma16(qpr[ks], *(const bh8*)&WB[SWZ(e*16 + l15, 256 + k0, 512)], gi[e]);
    }
    #pragma unroll
    for (int r = 0; r < 4; ++r) {
      float rr = sigmf_(gi[0][r] + bk0v[0] + gh0a[0][r] + bh0v[0]);
      float zz = sigmf_(gi[1][r] + bk0v[1] + gh0a[1][r] + bh0v[1]);
      float nn = tanhf(gi[2][r] + bk0v[2] + rr*(gh0a[2][r] + bh0v[2]));
      float hn = (1.f - zz)*nn + zz*h0s[r];
      h0s[r] = hn;
      stsh(h0b + pst + ((crow0 + r) << 4), f2bf(hn));
    }
    ++epoch;
    wbar_arrive(flags, g, wave, lane, epoch);
    // shadow: prefetch next step's x row (plain cached loads, after the drain)
    if (t + 1 < T_STEPS) {
      const unsigned short* xq = Xp + (size_t)(t + 1) * (NB*HID);
      #pragma unroll
      for (int j = 0; j < 8; ++j) xpr[j] = *(const bh8*)(xq + (size_t)arow*HID + j*32 + koff);
    }
    wbar_wait(flags, wave, lane, epoch);

    // ---------- Phase C: gi1 = h0@Wih1^T + bih1 ; h1 = GRU(gi1, gh1a, h1s) ----------
    bh8 h0n[8];
    #pragma unroll
    for (int j = 0; j < 8; ++j) h0n[j] = ldsh(h0b + BADDR(arow, j*32 + koff));
    waitv0();
    f32x4 gi1[3] = {zero, zero, zero};
    #pragma unroll
    for (int ks = 0; ks < 8; ++ks) {
      int k0 = ks*32 + koff;
      #pragma unroll
      for (int e = 0; e < 3; ++e)
        gi1[e] = mfma16(h0n[ks], *(const bh8*)&WI1[SWZ(e*16 + l15, k0, 256)], gi1[e]);
    }
    unsigned short* h1next = H1 + (size_t)(t + 1) * (NB*HID);
    #pragma unroll
    for (int r = 0; r < 4; ++r) {
      float rr = sigmf_(gi1[0][r] + bi1v[0] + gh1a[0][r] + bh1v[0]);
      float zz = sigmf_(gi1[1][r] + bi1v[1] + gh1a[1][r] + bh1v[1]);
      float nn = tanhf(gi1[2][r] + bi1v[2] + rr*(gh1a[2][r] + bh1v[2]));
      float hv = (1.f - zz)*nn + zz*h1s[r];
      h1s[r] = hv;
      stsh(h1next + pst + ((crow0 + r) << 4), f2bf(hv));
    }
    ++epoch;
    wbar_arrive(flags, g, wave, lane, epoch);
    // shadow: gh0a(t+1) from h0n + aQ1p(t+1) from xpr(t+1)
    if (t + 1 < T_STEPS) {
      gh0a[0] = zero; gh0a[1] = zero; gh0a[2] = zero;
      aQ1p = zero;
      #pragma unroll
      for (int ks = 0; ks < 8; ++ks) {
        int k0 = ks*32 + koff;
        #pragma unroll
        for (int e = 0; e < 3; ++e)
          gh0a[e] = mfma16(h0n[ks], *(const bh8*)&WH0[SWZ(e*16 + l15, k0, 256)], gh0a[e]);
        aQ1p = mfma16(xpr[ks], *(const bh8*)&WQ[SWZ(l15, 256 + k0, 512)], aQ1p);
      }
    }
    wbar_wait(flags, wave, lane, epoch);
  }

  // final hidden: each thread writes its own (row, col) cells from registers
  #pragma unroll
  for (int r = 0; r < 4; ++r) {
    int row = crow0 + r;
    outHid[(size_t)row*HID + col]         = h0s[r];
    outHid[16384 + (size_t)row*HID + col] = h1s[r];
  }
}

// ---------------- KL reduction ----------------
__global__ void kl1(const float* __restrict__ Q, const unsigned short* __restrict__ Ppb,
                    float* __restrict__ part) {
  const int m0 = blockIdx.x * 64;
  float s = 0.f;
  for (int i = threadIdx.x; i < 64*128; i += 256) {
    int m = m0 + (i >> 7), j = i & 127;
    float qm = Q[(size_t)m*256 + j],        ql = Q[(size_t)m*256 + 128 + j];
    float pm = bf2f(Ppb[(size_t)m*256 + j]), pl = bf2f(Ppb[(size_t)m*256 + 128 + j]);
    float d = qm - pm;
    s += 0.5f * (pl - ql + (expf(ql) + d*d) * expf(-pl) - 1.f);
  }
  for (int o = 32; o > 0; o >>= 1) s += __shfl_down(s, o);
  __shared__ float red[4];
  if ((threadIdx.x & 63) == 0) red[threadIdx.x >> 6] = s;
  __syncthreads();
  if (threadIdx.x == 0) part[blockIdx.x] = red[0] + red[1] + red[2] + red[3];
}
__global__ void kl2(const float* __restrict__ part, float* __restrict__ out) {
  float s = 0.f;
  for (int i = threadIdx.x; i < 512; i += 256) s += part[i];
  for (int o = 32; o > 0; o >>= 1) s += __shfl_down(s, o);
  __shared__ float red[4];
  if ((threadIdx.x & 63) == 0) red[threadIdx.x >> 6] = s;
  __syncthreads();
  if (threadIdx.x == 0) out[0] = (red[0] + red[1] + red[2] + red[3]) / 32768.f;
}

// ---------------- host launch ----------------
extern "C" void kernel_launch(void* const* d_in, const int* in_sizes, int n_in,
                              void* d_out, int out_size, void* d_ws, size_t ws_size,
                              hipStream_t stream) {
  const float* x_seq  = (const float*)d_in[0];
  const float* hidden = (const float*)d_in[1];
  const float* Wp   = (const float*)d_in[2];  const float* bp   = (const float*)d_in[3];
  const float* Wih0 = (const float*)d_in[4];  const float* Whh0 = (const float*)d_in[5];
  const float* bih0 = (const float*)d_in[6];  const float* bhh0 = (const float*)d_in[7];
  const float* Wih1 = (const float*)d_in[8];  const float* Whh1 = (const float*)d_in[9];
  const float* bih1 = (const float*)d_in[10]; const float* bhh1 = (const float*)d_in[11];
  const float* Wpr1 = (const float*)d_in[12]; const float* bpr1 = (const float*)d_in[13];
  const float* Wpr2 = (const float*)d_in[14]; const float* bpr2 = (const float*)d_in[15];
  const float* Wpo1 = (const float*)d_in[16]; const float* bpo1 = (const float*)d_in[17];
  const float* Wpo2 = (const float*)d_in[18]; const float* bpo2 = (const float*)d_in[19];
  const float* Wd1  = (const float*)d_in[20]; const float* bd1  = (const float*)d_in[21];
  const float* Wd2  = (const float*)d_in[22]; const float* bd2  = (const float*)d_in[23];

  char* ws = (char*)d_ws;
  char* Ob = (char*)d_out;
  float* O = (float*)d_out;

  // d_out doubles as scratch (fully rewritten by decoder GEMM at the end):
  unsigned short* Xp  = (unsigned short*)(Ob + 0);                      // 16 MiB [T][64][256]
  unsigned short* QP1 = (unsigned short*)(Ob + (16u << 20));            // 16 MiB blocked
  unsigned short* H1  = (unsigned short*)(Ob + (32u << 20));            // 16.03 MiB blocked (T+1)
  float*          Q   = (float*)         (Ob + (64u << 20));            // 32 MiB f32
  unsigned short* P1b = (unsigned short*)(Ob + (96u << 20));            // 16 MiB
  unsigned short* Ppb = (unsigned short*)(Ob + (112u << 20));           // 16 MiB

  // d_ws layout (~20.6 MB)
  unsigned short* D1b     = (unsigned short*)(ws + 0);                  // 16 MiB
  char* wb = ws + 16777216;
  unsigned short* Wp_b    = (unsigned short*)(wb + 0);
  unsigned short* Wpo1cat = (unsigned short*)(wb + 262144);
  unsigned short* Whh0_b  = (unsigned short*)(wb + 524288);
  unsigned short* Whh1_b  = (unsigned short*)(wb + 917504);
  unsigned short* Wih1_b  = (unsigned short*)(wb + 1310720);
  unsigned short* WBcat   = (unsigned short*)(wb + 1703936);
  unsigned short* Wpo2_b  = (unsigned short*)(wb + 2490368);
  unsigned short* Wpr1_b  = (unsigned short*)(wb + 2621440);
  unsigned short* Wpr2_b  = (unsigned short*)(wb + 2752512);
  unsigned short* Wd1cat  = (unsigned short*)(wb + 2883584);
  unsigned short* Wd2_b   = (unsigned short*)(wb + 3080192);
  float*    bk0    = (float*)(ws + 20381696);
  unsigned short* h0b = (unsigned short*)(ws + 20515840);               // 32 KiB blocked
  unsigned* flags  = (unsigned*)(ws + 20548608);   // 2048 dwords (64 flags, 128B apart)
  float*    klpart = (float*)(ws + 20557056);

  // ---- prep ----
  PrepArgs pa;
  pa.hidden = hidden;
  pa.Wp = Wp; pa.Wpo1 = Wpo1; pa.Whh0 = Whh0; pa.Whh1 = Whh1; pa.Wih1 = Wih1;
  pa.Wih0 = Wih0; pa.Wpo2 = Wpo2; pa.Wpr1 = Wpr1; pa.Wpr2 = Wpr2; pa.Wd1 = Wd1; pa.Wd2 = Wd2;
  pa.Wp_b = Wp_b; pa.Wpo1cat = Wpo1cat; pa.Whh0_b = Whh0_b; pa.Whh1_b = Whh1_b;
  pa.Wih1_b = Wih1_b; pa.WBcat = WBcat; pa.Wpo2_b = Wpo2_b; pa.Wpr1_b = Wpr1_b;
  pa.Wpr2_b = Wpr2_b; pa.Wd1cat = Wd1cat; pa.Wd2_b = Wd2_b;
  pa.H1_0 = H1; pa.h0b = h0b; pa.flags = flags;
  prep1<<<dim3(64, 16), 256, 0, stream>>>(pa);
  prep2<<<768, 256, 0, stream>>>(Wih0, Wpo2, bih0, bpo2, WBcat, bk0);

  // ---- x-projection: Xp[t][b][:] = x_seq@Wp^T + bp (bf16, bt-transposed) ----
  gemm_k<2, 1, 0><<<dim3(512, 4), 256, 0, stream>>>(
      x_seq, 512, 512, nullptr, 0, 0, Wp_b, bp, Xp, 32768, 256);

  // ---- sequential scan (persistent, 16 WGs, per-wave barriers, blocked exchange) ----
  (void)hipFuncSetAttribute((const void*)seq_kernel,
                            hipFuncAttributeMaxDynamicSharedMemorySize, SEQ_LDS_BYTES);
  seq_kernel<<<NWG, 256, SEQ_LDS_BYTES, stream>>>(
      Wpo1cat, Whh0_b, Whh1_b, WBcat, Wih1_b,
      bpo1, bhh0, bhh1, bih1, bk0, hidden,
      Xp, QP1, H1, h0b, flags, O + 33554433);

  // ---- deferred parallel phase ----
  // posterior q (f32) from blocked QP1
  gemm_k<0, 3, 0><<<dim3(512, 4), 256, 0, stream>>>(
      QP1, 0, 256, nullptr, 0, 0, Wpo2_b, bpo2, Q, 32768, 256);
  // prior layer 1 from blocked H1 slots 0..T-1
  gemm_k<3, 3, 0><<<dim3(512, 4), 256, 0, stream>>>(
      H1, 0, 256, nullptr, 0, 0, Wpr1_b, bpr1, P1b, 32768, 256);
  // prior layer 2 -> bf16
  gemm_k<1, 0, 0><<<dim3(512, 4), 256, 0, stream>>>(
      P1b, 256, 256, nullptr, 0, 0, Wpr2_b, bpr2, Ppb, 32768, 256);
  kl1<<<512, 256, 0, stream>>>(Q, Ppb, klpart);
  kl2<<<1, 256, 0, stream>>>(klpart, O + 33554432);
  // decoder layer 1: gelu([h1_t | z_t]@Wd1^T + bd1) from blocked H1 slots 1..T + Q
  gemm_k<3, 3, 1><<<dim3(512, 4), 256, 0, stream>>>(
      H1 + 16384, 0, 256, Q, 256, 128, Wd1cat, bd1, D1b, 32768, 256);
  // decoder layer 2 -> pred_mu / pred_lv (rewrites all of d_out scratch)
  gemm_k<4, 0, 0><<<dim3(512, 16), 256, 0, stream>>>(
      D1b, 256, 256, nullptr, 0, 0, Wd2_b, bd2, (void*)O, 32768, 1024);

  (void)in_sizes; (void)n_in; (void)out_size; (void)ws_size;
}